// Round 1
// 148.447 us; speedup vs baseline: 1.0581x; 1.0581x over previous
//
#include <hip/hip_runtime.h>
#include <hip/hip_bf16.h>

typedef unsigned short u16;
typedef short bf16x8 __attribute__((ext_vector_type(8)));
typedef float f32x4 __attribute__((ext_vector_type(4)));
typedef int   i32x4 __attribute__((ext_vector_type(4)));

#define NB 8
#define NT 1024
#define ND 512
#define KSEL 307
#define PSTR 152   // attn P LDS row stride (elems)
#define TSTR 136   // gemm_wh transpose LDS row stride (elems)

__device__ __forceinline__ float bf2f(u16 u){
  union { unsigned int i; float f; } c; c.i = ((unsigned int)u) << 16; return c.f;
}
__device__ __forceinline__ u16 f2bf(float f){
  __hip_bfloat16 h = __float2bfloat16(f);
  u16 u; __builtin_memcpy(&u, &h, 2); return u;
}

// ---------- prep: x f32 -> bf16 (+ row L2 norms), W -> WbT[h][f][k] bf16,
//            W2 -> W2T[n][k] bf16.  Removes all strided f32 loads + cvt from
//            the GEMM hot loops.
__global__ void k_prep(const float* __restrict__ x, const float* __restrict__ Wf,
                       const float* __restrict__ W2f, u16* __restrict__ xbf,
                       u16* __restrict__ WbT, u16* __restrict__ W2T,
                       float* __restrict__ mags){
  __shared__ float tile[64][65];
  int bx = blockIdx.x;
  int tid = threadIdx.x;
  if (bx < 512){
    // x convert + mags: block handles 16 rows; one wave per 4 rows
    int wv = tid >> 6, lane = tid & 63;
#pragma unroll
    for (int rr = 0; rr < 4; rr++){
      int row = bx * 16 + wv * 4 + rr;
      const float* xp = &x[(size_t)row * 512 + lane * 8];
      f32x4 u0 = *(const f32x4*)xp;
      f32x4 u1 = *(const f32x4*)(xp + 4);
      u16 pk[8];
      float s = 0.f;
#pragma unroll
      for (int q = 0; q < 4; q++){
        s += u0[q]*u0[q] + u1[q]*u1[q];
        pk[q] = f2bf(u0[q]); pk[4+q] = f2bf(u1[q]);
      }
      *(bf16x8*)&xbf[(size_t)row * 512 + lane * 8] = *(const bf16x8*)pk;
#pragma unroll
      for (int m = 1; m < 64; m <<= 1) s += __shfl_xor(s, m, 64);
      if (lane == 0) mags[row] = sqrtf(s);
    }
  } else {
    // 64x64 f32 tile transpose-convert: 64 tiles for W, 64 for W2
    int tb = bx - 512;
    const float* src; u16* dst; int srcld, dstld;
    if (tb < 64){
      int h = tb >> 3, kt = (tb & 7) * 64;
      src = Wf + ((size_t)h << 15) + (size_t)kt * 64;  srcld = 64;   // [k][f]
      dst = WbT + ((size_t)h * 64) * 512 + kt;         dstld = 512;  // [f][k]
    } else {
      int t2 = tb - 64;
      int kt = (t2 >> 3) * 64, n0 = (t2 & 7) * 64;
      src = W2f + (size_t)kt * 512 + n0;  srcld = 512;               // [k][n]
      dst = W2T + (size_t)n0 * 512 + kt;  dstld = 512;               // [n][k]
    }
    int r = tid >> 6, cl = tid & 63;
#pragma unroll
    for (int p = 0; p < 16; p++)
      tile[r + p*4][cl] = src[(size_t)(r + p*4) * srcld + cl];
    __syncthreads();
#pragma unroll
    for (int p = 0; p < 16; p++){
      int orow = r + p*4;                       // output row = source col
      dst[(size_t)orow * dstld + cl] = f2bf(tile[cl][orow]);
    }
  }
}

// ---------- exact top-k selection by ranking; 4 threads per t, 64 t per block
//            + fused cn zeroing (block (b,by) owns cn[b*512 + by*32 ..+32])
__global__ void k_select(const float* __restrict__ mags, int* __restrict__ sel,
                         float* __restrict__ cn){
  __shared__ float sm[NT];
  int b = blockIdx.x;
  int tid = threadIdx.x;
  if (tid < 32) cn[b * ND + blockIdx.y * 32 + tid] = 0.f;
  for (int i = tid; i < NT; i += 256) sm[i] = mags[b * NT + i];
  __syncthreads();
  int tl = tid >> 2, tq = tid & 3;
  int t = blockIdx.y * 64 + tl;
  float m = sm[t];
  int cnt = 0;
  int s0 = tq * 256;
  for (int s = s0; s < s0 + 256; s++){
    float v = sm[s];
    cnt += (v > m) || (v == m && s < t);
  }
  cnt += __shfl_xor(cnt, 1, 64);
  cnt += __shfl_xor(cnt, 2, 64);
  if (tq == 0) sel[b * NT + t] = (cnt < KSEL) ? 1 : 0;
}

// ---------- MFMA bf16 GEMM: Wh = xbf @ WbT^T ; tile 128(t) x 64(f = one head)
//   Pure bf16 staging (16B coalesced loads, register prefetch of next K-tile).
//   epilogue fuses: es/ed edge dots, transposed bf16 WhT write
__launch_bounds__(256, 3)
__global__ void k_gemm_wh(const u16* __restrict__ xbf, const u16* __restrict__ WbT,
                          const float* __restrict__ a_src, const float* __restrict__ a_dst,
                          u16* __restrict__ WhT, float* __restrict__ es, float* __restrict__ ed){
  __shared__ u16 smem[8704];         // 17408 B; As(5120)+Bs(2560) alias Tr(64*TSTR)
  u16* As = smem;                    // 128 x 40
  u16* Bs = smem + 5120;             // 64 x 40
  int m0 = blockIdx.x * 128;         // t-block
  int h  = blockIdx.y;               // head (n0 = h*64)
  int tid = threadIdx.x;
  int wv = tid >> 6, lane = tid & 63;
  int quad = lane >> 4, lr = lane & 15;
  f32x4 acc[2][4] = {};
  int ar0 = (tid * 8) >> 5, ac = (tid * 8) & 31;   // rows 0..63, k-offset 0..24
  const u16* ap0 = &xbf[(size_t)(m0 + ar0) * 512 + ac];
  const u16* ap1 = ap0 + (size_t)64 * 512;
  const u16* bp  = &WbT[(size_t)(h * 64 + ar0) * 512 + ac];
  bf16x8 ra0 = *(const bf16x8*)ap0;
  bf16x8 ra1 = *(const bf16x8*)ap1;
  bf16x8 rb  = *(const bf16x8*)bp;
  for (int kt = 0; kt < 512; kt += 32){
    __syncthreads();
    *(bf16x8*)&As[ar0*40 + ac]        = ra0;
    *(bf16x8*)&As[(ar0 + 64)*40 + ac] = ra1;
    *(bf16x8*)&Bs[ar0*40 + ac]        = rb;
    __syncthreads();
    if (kt < 480){
      ra0 = *(const bf16x8*)(ap0 + kt + 32);
      ra1 = *(const bf16x8*)(ap1 + kt + 32);
      rb  = *(const bf16x8*)(bp  + kt + 32);
    }
    bf16x8 af[2], bfr[4];
#pragma unroll
    for (int i = 0; i < 2; i++) af[i] = *(const bf16x8*)&As[(wv*32 + i*16 + lr)*40 + quad*8];
#pragma unroll
    for (int i = 0; i < 4; i++) bfr[i] = *(const bf16x8*)&Bs[(i*16 + lr)*40 + quad*8];
#pragma unroll
    for (int mi = 0; mi < 2; mi++)
#pragma unroll
      for (int ni = 0; ni < 4; ni++)
        acc[mi][ni] = __builtin_amdgcn_mfma_f32_16x16x32_bf16(af[mi], bfr[ni], acc[mi][ni], 0, 0, 0);
  }
  // ---- epilogue 1: edge dot products (wave owns rows wv*32..+32, full head width)
  float asv[4], adv[4];
#pragma unroll
  for (int ni = 0; ni < 4; ni++){
    asv[ni] = a_src[h*64 + ni*16 + lr];
    adv[ni] = a_dst[h*64 + ni*16 + lr];
  }
#pragma unroll
  for (int mi = 0; mi < 2; mi++)
#pragma unroll
    for (int r = 0; r < 4; r++){
      float pes = 0.f, ped = 0.f;
#pragma unroll
      for (int ni = 0; ni < 4; ni++){
        pes += acc[mi][ni][r] * asv[ni];
        ped += acc[mi][ni][r] * adv[ni];
      }
#pragma unroll
      for (int mofs = 1; mofs < 16; mofs <<= 1){
        pes += __shfl_xor(pes, mofs, 64);
        ped += __shfl_xor(ped, mofs, 64);
      }
      if (lr == 0){
        int rowg = m0 + wv*32 + mi*16 + quad*4 + r;
        int bb_ = rowg >> 10, tt = rowg & 1023;
        es[(bb_ * 8 + h) * NT + tt] = pes;
        ed[(bb_ * 8 + h) * NT + tt] = ped;
      }
    }
  // ---- epilogue 2: bf16 transpose via LDS -> WhT[(b*512 + h*64 + f)][t]
  __syncthreads();
  u16* Tr = smem;   // [f][t], stride TSTR
#pragma unroll
  for (int mi = 0; mi < 2; mi++)
#pragma unroll
    for (int ni = 0; ni < 4; ni++){
      int fl = ni*16 + lr;
      int tl = wv*32 + mi*16 + quad*4;
#pragma unroll
      for (int r = 0; r < 4; r++) Tr[fl*TSTR + tl + r] = f2bf(acc[mi][ni][r]);
    }
  __syncthreads();
  int f = tid >> 2, seg = tid & 3;
  int b_ = m0 >> 10;
  u16* dst = &WhT[(b_ * 512 + h * 64 + f) * NT + (m0 & 1023) + seg*32];
  const u16* srcp = &Tr[f*TSTR + seg*32];
#pragma unroll
  for (int k8 = 0; k8 < 4; k8++)
    *(bf16x8*)(dst + k8*8) = *(const bf16x8*)(srcp + k8*8);
}

// ---------- banded masked attention via MFMA + elu + signed-sqrt -> t2b (bf16)
//            + fused column sum-of-squares (atomicAdd into cn)
__launch_bounds__(256)
__global__ void k_attn(const u16* __restrict__ WhT, const float* __restrict__ es,
                       const float* __restrict__ ed, const int* __restrict__ sel,
                       u16* __restrict__ t2b, float* __restrict__ cn){
  __shared__ u16 P[64 * PSTR];
  __shared__ float edw[144];
  __shared__ int   selw[144];
  __shared__ float esw[64];
  __shared__ float swv[64];
  int bh = blockIdx.x;               // b*8+h
  int b = bh >> 3;
  int t0 = blockIdx.y * 64;
  int tid = threadIdx.x;
  int wv = tid >> 6, lane = tid & 63;
  int quad = lane >> 4, lr = lane & 15;
  int s_base = t0 - 40;
  for (int i = tid; i < 144; i += 256){
    int s = s_base + i;
    bool ok = (s >= 0 && s < NT);
    edw[i]  = ok ? ed[bh * NT + s] : 0.f;
    selw[i] = ok ? sel[b * NT + s] : 0;
  }
  if (tid < 64) esw[tid] = es[bh * NT + t0 + tid];
  {
    i32x4 z = {};
    for (int i = lane; i < 304; i += 64){
      int r16 = i / 19, c16 = i - r16 * 19;
      *(i32x4*)&P[(16*wv + r16) * PSTR + c16 * 8] = z;
    }
  }
  __syncthreads();
  {
    int tl = 16*wv + (lane >> 2);
    int q = lane & 3;
    float e_t = esw[tl];
    int sel_t = selw[tl + 40];
    float part = 0.f;
    for (int j = q; j <= 80; j += 4){
      int sw = tl + j;
      int s = s_base + sw;
      float w = 0.f;
      if (s >= 0 && s < NT && (sel_t | selw[sw])){
        float v = e_t + edw[sw];
        v = v > 0.f ? v : 0.2f * v;
        v = fminf(v, 60.f);
        w = bf2f(f2bf(__expf(v)));
      }
      part += w;
      if (w != 0.f) P[tl * PSTR + sw] = f2bf(w);
    }
    part += __shfl_xor(part, 1, 64);
    part += __shfl_xor(part, 2, 64);
    if (q == 0) swv[tl] = part;
  }
  f32x4 acc[4] = {};
  const u16* vbase = WhT + (bh * 64) * NT;
#pragma unroll
  for (int ks = 0; ks < 96; ks += 32){
    bf16x8 afr = *(const bf16x8*)&P[(16*wv + lr) * PSTR + 16*wv + ks + quad*8];
    int tb = s_base + 16*wv + ks + quad*8;
    bool ok = (tb >= 0) && (tb < NT);
    bf16x8 zf = {};
#pragma unroll
    for (int jn = 0; jn < 4; jn++){
      bf16x8 bfr = ok ? *(const bf16x8*)&vbase[(16*jn + lr) * NT + tb] : zf;
      acc[jn] = __builtin_amdgcn_mfma_f32_16x16x32_bf16(afr, bfr, acc[jn], 0, 0, 0);
    }
  }
#pragma unroll
  for (int jn = 0; jn < 4; jn++){
    float ssum = 0.f;
#pragma unroll
    for (int r = 0; r < 4; r++){
      int t_loc = 16*wv + quad*4 + r;
      float sw_ = swv[t_loc];
      float hp = acc[jn][r] / (sw_ > 0.f ? sw_ : 1.f);
      hp = hp > 0.f ? hp : (__expf(hp) - 1.f);
      float o = hp >= 0.f ? sqrtf(hp) : -sqrtf(-hp);
      ssum += o * o;
      t2b[(b * NT + t0 + t_loc) * ND + (bh & 7) * 64 + 16*jn + lr] = f2bf(o);
    }
    ssum += __shfl_xor(ssum, 16, 64);
    ssum += __shfl_xor(ssum, 32, 64);
    if (quad == 0) atomicAdd(&cn[b * ND + (bh & 7) * 64 + 16*jn + lr], ssum);
  }
}

// ---------- GEMM2: Y = (t2b*scl) @ W2 + x + b2 ; tile 128 x 64 ; fused LN partials
//   B from pre-transposed bf16 W2T[n][k]; A scaled at LDS-store time.
__launch_bounds__(256, 3)
__global__ void k_gemm2(const u16* __restrict__ A, const u16* __restrict__ W2T,
                        const float* __restrict__ xres, const float* __restrict__ b2,
                        const float* __restrict__ cn, float* __restrict__ Y,
                        float* __restrict__ rsum, float* __restrict__ rqsum){
  __shared__ u16 As[128 * 40];
  __shared__ u16 Bs[64 * 40];
  __shared__ float scl[512];
  int m0 = blockIdx.x * 128, n0 = blockIdx.y * 64;
  int tid = threadIdx.x;
  int wv = tid >> 6, lane = tid & 63;
  int quad = lane >> 4, lr = lane & 15;
  int bb0 = (m0 >> 10) << 9;          // b*512
  for (int i = tid; i < 512; i += 256){
    float nv = sqrtf(cn[bb0 + i]);
    scl[i] = 1.f / fmaxf(nv, 1e-12f);
  }
  f32x4 acc[2][4] = {};
  int ar0 = (tid * 8) >> 5, ac = (tid * 8) & 31;
  const u16* ap0 = &A[(size_t)(m0 + ar0) * 512 + ac];
  const u16* ap1 = ap0 + (size_t)64 * 512;
  const u16* bp  = &W2T[(size_t)(n0 + ar0) * 512 + ac];
  bf16x8 ra0 = *(const bf16x8*)ap0;
  bf16x8 ra1 = *(const bf16x8*)ap1;
  bf16x8 rb  = *(const bf16x8*)bp;
  for (int kt = 0; kt < 512; kt += 32){
    __syncthreads();
    {
      u16 pk0[8], pk1[8];
#pragma unroll
      for (int q = 0; q < 8; q++){
        float sv = scl[kt + ac + q];
        pk0[q] = f2bf(bf2f((u16)ra0[q]) * sv);
        pk1[q] = f2bf(bf2f((u16)ra1[q]) * sv);
      }
      *(bf16x8*)&As[ar0*40 + ac]        = *(const bf16x8*)pk0;
      *(bf16x8*)&As[(ar0 + 64)*40 + ac] = *(const bf16x8*)pk1;
      *(bf16x8*)&Bs[ar0*40 + ac]        = rb;
    }
    __syncthreads();
    if (kt < 480){
      ra0 = *(const bf16x8*)(ap0 + kt + 32);
      ra1 = *(const bf16x8*)(ap1 + kt + 32);
      rb  = *(const bf16x8*)(bp  + kt + 32);
    }
    bf16x8 af[2], bfr[4];
#pragma unroll
    for (int i = 0; i < 2; i++) af[i] = *(const bf16x8*)&As[(wv*32 + i*16 + lr)*40 + quad*8];
#pragma unroll
    for (int i = 0; i < 4; i++) bfr[i] = *(const bf16x8*)&Bs[(i*16 + lr)*40 + quad*8];
#pragma unroll
    for (int mi = 0; mi < 2; mi++)
#pragma unroll
      for (int ni = 0; ni < 4; ni++)
        acc[mi][ni] = __builtin_amdgcn_mfma_f32_16x16x32_bf16(af[mi], bfr[ni], acc[mi][ni], 0, 0, 0);
  }
  float b2v[4];
#pragma unroll
  for (int ni = 0; ni < 4; ni++) b2v[ni] = b2[n0 + ni*16 + lr];
#pragma unroll
  for (int mi = 0; mi < 2; mi++){
    int rgb = m0 + wv*32 + mi*16 + quad*4;
#pragma unroll
    for (int r = 0; r < 4; r++){
      int row = rgb + r;
      float rs = 0.f, rq = 0.f;
#pragma unroll
      for (int ni = 0; ni < 4; ni++){
        int cg = n0 + ni*16 + lr;
        int idx = row * 512 + cg;
        float yv = acc[mi][ni][r] + xres[idx] + b2v[ni];
        Y[idx] = yv;
        rs += yv; rq += yv * yv;
      }
#pragma unroll
      for (int m2 = 1; m2 < 16; m2 <<= 1){
        rs += __shfl_xor(rs, m2, 64);
        rq += __shfl_xor(rq, m2, 64);
      }
      if (lr == 0){
        atomicAdd(&rsum[row], rs);
        atomicAdd(&rqsum[row], rq);
      }
    }
  }
}

// ---------- LN apply (stats precomputed) + transpose; block = 64 t x 128 d
__global__ void k_outln(const float* __restrict__ Y, const float* __restrict__ rsum,
                        const float* __restrict__ rqsum, const float* __restrict__ g,
                        const float* __restrict__ bb, float* __restrict__ out){
  __shared__ float mus[64], rss[64];
  __shared__ float tile[64 * 65];
  int t0 = blockIdx.x * 64, b = blockIdx.y;
  int cbase = blockIdx.z * 128;
  int tid = threadIdx.x;
  if (tid < 64){
    int row = b * NT + t0 + tid;
    float m = rsum[row] * (1.f/512.f);
    float var = rqsum[row] * (1.f/512.f) - m * m;
    mus[tid] = m;
    rss[tid] = 1.f / sqrtf(var + 1e-5f);
  }
  __syncthreads();
  int j = tid & 63, i0 = tid >> 6;
  for (int c0 = cbase; c0 < cbase + 128; c0 += 64){
#pragma unroll
    for (int k = 0; k < 16; k++){
      int i = i0 + k * 4;
      float v = (Y[(b * NT + t0 + i) * ND + c0 + j] - mus[i]) * rss[i] * g[c0 + j] + bb[c0 + j];
      tile[i * 65 + j] = v;
    }
    __syncthreads();
#pragma unroll
    for (int k = 0; k < 16; k++){
      int jj = i0 + k * 4;   // d-local
      out[(b * ND + c0 + jj) * NT + t0 + j] = tile[j * 65 + jj];
    }
    __syncthreads();
  }
}

extern "C" void kernel_launch(void* const* d_in, const int* in_sizes, int n_in,
                              void* d_out, int out_size, void* d_ws, size_t ws_size,
                              hipStream_t stream) {
  (void)in_sizes; (void)n_in; (void)out_size; (void)ws_size;
  const float* x     = (const float*)d_in[0];
  const float* W     = (const float*)d_in[1];
  const float* a_src = (const float*)d_in[2];
  const float* a_dst = (const float*)d_in[3];
  const float* W2    = (const float*)d_in[4];
  const float* b2    = (const float*)d_in[5];
  const float* ln_g  = (const float*)d_in[6];
  const float* ln_b  = (const float*)d_in[7];
  char* ws = (char*)d_ws;
  int*   sel   = (int*)  (ws + 256);
  float* mags  = (float*)(ws + 33024);
  float* es    = (float*)(ws + 1124608);
  float* ed    = (float*)(ws + 1386752);
  float* cn    = (float*)(ws + 1648896);   // 16 KB (zeroed in k_select)
  float* rsum  = (float*)(ws + 1665280);   // 32 KB
  float* rqsum = (float*)(ws + 1698048);   // 32 KB
  u16*   WhT   = (u16*)  (ws + 2097152);   // 8 MB; dead after k_attn
  u16*   t2b   = (u16*)  (ws + 18874368);  // 8 MB
  float* Y     = (float*)(ws + 2097152);   // 16 MB; overlays WhT after dead
  u16*   xbf   = (u16*)  (ws + 27262976);  // 8 MB bf16(x)
  u16*   WbT   = (u16*)  (ws + 35651584);  // 512 KB bf16 W[h][f][k]
  u16*   W2T   = (u16*)  (ws + 36175872);  // 512 KB bf16 W2[n][k]
  float* out   = (float*)d_out;

  hipMemsetAsync(rsum, 0, 65536, stream);  // rsum + rqsum
  k_prep     <<<dim3(640), 256, 0, stream>>>(x, W, W2, xbf, WbT, W2T, mags);
  k_select   <<<dim3(NB, 16), 256, 0, stream>>>(mags, sel, cn);
  k_gemm_wh  <<<dim3(64, 8), 256, 0, stream>>>(xbf, WbT, a_src, a_dst, WhT, es, ed);
  k_attn     <<<dim3(64, 16), 256, 0, stream>>>(WhT, es, ed, sel, t2b, cn);
  k_gemm2    <<<dim3(64, 8), 256, 0, stream>>>(t2b, W2T, x, b2, cn, Y, rsum, rqsum);
  k_outln    <<<dim3(16, NB, 4), 256, 0, stream>>>(Y, rsum, rqsum, ln_g, ln_b, out);
}

// Round 2
// 147.483 us; speedup vs baseline: 1.0650x; 1.0065x over previous
//
#include <hip/hip_runtime.h>
#include <hip/hip_bf16.h>

typedef unsigned short u16;
typedef short bf16x8 __attribute__((ext_vector_type(8)));
typedef float f32x4 __attribute__((ext_vector_type(4)));
typedef int   i32x4 __attribute__((ext_vector_type(4)));

#define NB 8
#define NT 1024
#define ND 512
#define KSEL 307
#define PSTR 152   // attn P LDS row stride (elems)
#define TSTR 136   // gemm_wh transpose LDS row stride (elems)

__device__ __forceinline__ float bf2f(u16 u){
  union { unsigned int i; float f; } c; c.i = ((unsigned int)u) << 16; return c.f;
}
__device__ __forceinline__ u16 f2bf(float f){
  __hip_bfloat16 h = __float2bfloat16(f);
  u16 u; __builtin_memcpy(&u, &h, 2); return u;
}

// ---------- exact top-k selection by ranking; 4 threads per t, 64 t per block
__global__ void k_select(const float* __restrict__ mags, int* __restrict__ sel){
  __shared__ float sm[NT];
  int b = blockIdx.x;
  int tid = threadIdx.x;
  for (int i = tid; i < NT; i += 256) sm[i] = mags[b * NT + i];
  __syncthreads();
  int tl = tid >> 2, tq = tid & 3;
  int t = blockIdx.y * 64 + tl;
  float m = sm[t];
  int cnt = 0;
  int s0 = tq * 256;
  for (int s = s0; s < s0 + 256; s++){
    float v = sm[s];
    cnt += (v > m) || (v == m && s < t);
  }
  cnt += __shfl_xor(cnt, 1, 64);
  cnt += __shfl_xor(cnt, 2, 64);
  if (tq == 0) sel[b * NT + t] = (cnt < KSEL) ? 1 : 0;
}

// ---------- MFMA bf16 GEMM: Wh = bf16(x) @ W ; tile 128(t) x 64(f = one head)
//   A staged from f32 x with inline cvt (+ sq for mags, h==0 only).
//   B staged COALESCED from f32 W[h][k][f] with LDS-transposed swizzled write.
//   Fused: cn zero (h==0 blocks), rsum/rqsum zero (h==1 blocks),
//          mags epilogue, es/ed edge dots, transposed bf16 WhT write.
__launch_bounds__(256, 3)
__global__ void k_gemm_wh(const float* __restrict__ x, const float* __restrict__ Wf,
                          const float* __restrict__ a_src, const float* __restrict__ a_dst,
                          u16* __restrict__ WhT, float* __restrict__ es, float* __restrict__ ed,
                          float* __restrict__ mags, float* __restrict__ cn,
                          float* __restrict__ rz){
  __shared__ u16 smem[8704];         // 17408 B; As(5120)+Bs(2560) alias Tr(64*TSTR)
  u16* As = smem;                    // 128 x 40
  u16* Bs = smem + 5120;             // 64 x 40 (k-chunks xor-swizzled)
  int m0 = blockIdx.x * 128;         // t-block
  int h  = blockIdx.y;               // head (n0 = h*64)
  int tid = threadIdx.x;
  // fused zero-init: cn consumed by k_attn, rsum/rqsum by k_gemm2 (both later kernels)
  if (h == 0 && tid < 64) cn[blockIdx.x * 64 + tid] = 0.f;
  if (h == 1) rz[blockIdx.x * 256 + tid] = 0.f;
  int wv = tid >> 6, lane = tid & 63;
  int quad = lane >> 4, lr = lane & 15;
  f32x4 acc[2][4] = {};
  float sq[2] = {0.f, 0.f};
  // A addressing: e = tid*8 (+2048) -> r = e>>5 in 0..63, c = e&31
  int ar = (tid * 8) >> 5, ac = (tid * 8) & 31;
  const float* xa0 = &x[(size_t)(m0 + ar) * 512 + ac];
  const float* xa1 = xa0 + (size_t)64 * 512;
  // B addressing: e = tid*8 -> kk = e>>6 in 0..31, f0 = e&63 (mult of 8)
  int kk = (tid * 8) >> 6, f0 = (tid * 8) & 63;
  const float* wb = &Wf[((size_t)h << 15) + (size_t)kk * 64 + f0];
  int bbase = f0 * 40 + (((kk >> 3) ^ ((f0 >> 3) & 3)) * 8) + (kk & 7);
  f32x4 pa0 = *(const f32x4*)xa0, pa1 = *(const f32x4*)(xa0 + 4);
  f32x4 pa2 = *(const f32x4*)xa1, pa3 = *(const f32x4*)(xa1 + 4);
  f32x4 pb0 = *(const f32x4*)wb,  pb1 = *(const f32x4*)(wb + 4);
  for (int kt = 0; kt < 512; kt += 32){
    __syncthreads();
    {
      u16 pk[8];
      if (h == 0){
#pragma unroll
        for (int q = 0; q < 4; q++) sq[0] += pa0[q]*pa0[q] + pa1[q]*pa1[q];
#pragma unroll
        for (int q = 0; q < 4; q++) sq[1] += pa2[q]*pa2[q] + pa3[q]*pa3[q];
      }
#pragma unroll
      for (int q = 0; q < 4; q++){ pk[q] = f2bf(pa0[q]); pk[4+q] = f2bf(pa1[q]); }
      *(bf16x8*)&As[ar*40 + ac] = *(const bf16x8*)pk;
#pragma unroll
      for (int q = 0; q < 4; q++){ pk[q] = f2bf(pa2[q]); pk[4+q] = f2bf(pa3[q]); }
      *(bf16x8*)&As[(ar + 64)*40 + ac] = *(const bf16x8*)pk;
#pragma unroll
      for (int q = 0; q < 4; q++) Bs[bbase + q*40]       = f2bf(pb0[q]);
#pragma unroll
      for (int q = 0; q < 4; q++) Bs[bbase + (q+4)*40]   = f2bf(pb1[q]);
    }
    __syncthreads();
    if (kt < 480){
      pa0 = *(const f32x4*)(xa0 + kt + 32); pa1 = *(const f32x4*)(xa0 + kt + 36);
      pa2 = *(const f32x4*)(xa1 + kt + 32); pa3 = *(const f32x4*)(xa1 + kt + 36);
      pb0 = *(const f32x4*)(wb + (size_t)(kt + 32) * 64);
      pb1 = *(const f32x4*)(wb + (size_t)(kt + 32) * 64 + 4);
    }
    bf16x8 af[2], bfr[4];
#pragma unroll
    for (int i = 0; i < 2; i++) af[i] = *(const bf16x8*)&As[(wv*32 + i*16 + lr)*40 + quad*8];
#pragma unroll
    for (int i = 0; i < 4; i++){
      int f = i*16 + lr;
      bfr[i] = *(const bf16x8*)&Bs[f*40 + ((quad ^ ((f >> 3) & 3)) * 8)];
    }
#pragma unroll
    for (int mi = 0; mi < 2; mi++)
#pragma unroll
      for (int ni = 0; ni < 4; ni++)
        acc[mi][ni] = __builtin_amdgcn_mfma_f32_16x16x32_bf16(af[mi], bfr[ni], acc[mi][ni], 0, 0, 0);
  }
  // ---- epilogue 0: row L2 norms (4 lanes per row), h==0 blocks only
  if (h == 0){
#pragma unroll
    for (int i = 0; i < 2; i++){
      float s = sq[i];
      s += __shfl_xor(s, 1, 64);
      s += __shfl_xor(s, 2, 64);
      if ((tid & 3) == 0) mags[m0 + i*64 + (tid >> 2)] = sqrtf(s);
    }
  }
  // ---- epilogue 1: edge dot products
  float asv[4], adv[4];
#pragma unroll
  for (int ni = 0; ni < 4; ni++){
    asv[ni] = a_src[h*64 + ni*16 + lr];
    adv[ni] = a_dst[h*64 + ni*16 + lr];
  }
#pragma unroll
  for (int mi = 0; mi < 2; mi++)
#pragma unroll
    for (int r = 0; r < 4; r++){
      float pes = 0.f, ped = 0.f;
#pragma unroll
      for (int ni = 0; ni < 4; ni++){
        pes += acc[mi][ni][r] * asv[ni];
        ped += acc[mi][ni][r] * adv[ni];
      }
#pragma unroll
      for (int mofs = 1; mofs < 16; mofs <<= 1){
        pes += __shfl_xor(pes, mofs, 64);
        ped += __shfl_xor(ped, mofs, 64);
      }
      if (lr == 0){
        int rowg = m0 + wv*32 + mi*16 + quad*4 + r;
        int bb_ = rowg >> 10, tt = rowg & 1023;
        es[(bb_ * 8 + h) * NT + tt] = pes;
        ed[(bb_ * 8 + h) * NT + tt] = ped;
      }
    }
  // ---- epilogue 2: bf16 transpose via LDS -> WhT[(b*512 + h*64 + f)][t]
  __syncthreads();
  u16* Tr = smem;   // [f][t], stride TSTR
#pragma unroll
  for (int mi = 0; mi < 2; mi++)
#pragma unroll
    for (int ni = 0; ni < 4; ni++){
      int fl = ni*16 + lr;
      int tl = wv*32 + mi*16 + quad*4;
#pragma unroll
      for (int r = 0; r < 4; r++) Tr[fl*TSTR + tl + r] = f2bf(acc[mi][ni][r]);
    }
  __syncthreads();
  int f = tid >> 2, seg = tid & 3;
  int b_ = m0 >> 10;
  u16* dst = &WhT[(b_ * 512 + h * 64 + f) * NT + (m0 & 1023) + seg*32];
  const u16* srcp = &Tr[f*TSTR + seg*32];
#pragma unroll
  for (int k8 = 0; k8 < 4; k8++)
    *(bf16x8*)(dst + k8*8) = *(const bf16x8*)(srcp + k8*8);
}

// ---------- banded masked attention via MFMA + elu + signed-sqrt -> t2b (bf16)
//            + fused column sum-of-squares (atomicAdd into cn)
__launch_bounds__(256)
__global__ void k_attn(const u16* __restrict__ WhT, const float* __restrict__ es,
                       const float* __restrict__ ed, const int* __restrict__ sel,
                       u16* __restrict__ t2b, float* __restrict__ cn){
  __shared__ u16 P[64 * PSTR];
  __shared__ float edw[144];
  __shared__ int   selw[144];
  __shared__ float esw[64];
  __shared__ float swv[64];
  int bh = blockIdx.x;               // b*8+h
  int b = bh >> 3;
  int t0 = blockIdx.y * 64;
  int tid = threadIdx.x;
  int wv = tid >> 6, lane = tid & 63;
  int quad = lane >> 4, lr = lane & 15;
  int s_base = t0 - 40;
  for (int i = tid; i < 144; i += 256){
    int s = s_base + i;
    bool ok = (s >= 0 && s < NT);
    edw[i]  = ok ? ed[bh * NT + s] : 0.f;
    selw[i] = ok ? sel[b * NT + s] : 0;
  }
  if (tid < 64) esw[tid] = es[bh * NT + t0 + tid];
  {
    i32x4 z = {};
    for (int i = lane; i < 304; i += 64){
      int r16 = i / 19, c16 = i - r16 * 19;
      *(i32x4*)&P[(16*wv + r16) * PSTR + c16 * 8] = z;
    }
  }
  __syncthreads();
  {
    int tl = 16*wv + (lane >> 2);
    int q = lane & 3;
    float e_t = esw[tl];
    int sel_t = selw[tl + 40];
    float part = 0.f;
    for (int j = q; j <= 80; j += 4){
      int sw = tl + j;
      int s = s_base + sw;
      float w = 0.f;
      if (s >= 0 && s < NT && (sel_t | selw[sw])){
        float v = e_t + edw[sw];
        v = v > 0.f ? v : 0.2f * v;
        v = fminf(v, 60.f);
        w = bf2f(f2bf(__expf(v)));
      }
      part += w;
      if (w != 0.f) P[tl * PSTR + sw] = f2bf(w);
    }
    part += __shfl_xor(part, 1, 64);
    part += __shfl_xor(part, 2, 64);
    if (q == 0) swv[tl] = part;
  }
  f32x4 acc[4] = {};
  const u16* vbase = WhT + (bh * 64) * NT;
#pragma unroll
  for (int ks = 0; ks < 96; ks += 32){
    bf16x8 afr = *(const bf16x8*)&P[(16*wv + lr) * PSTR + 16*wv + ks + quad*8];
    int tb = s_base + 16*wv + ks + quad*8;
    bool ok = (tb >= 0) && (tb < NT);
    bf16x8 zf = {};
#pragma unroll
    for (int jn = 0; jn < 4; jn++){
      bf16x8 bfr = ok ? *(const bf16x8*)&vbase[(16*jn + lr) * NT + tb] : zf;
      acc[jn] = __builtin_amdgcn_mfma_f32_16x16x32_bf16(afr, bfr, acc[jn], 0, 0, 0);
    }
  }
#pragma unroll
  for (int jn = 0; jn < 4; jn++){
    float ssum = 0.f;
#pragma unroll
    for (int r = 0; r < 4; r++){
      int t_loc = 16*wv + quad*4 + r;
      float sw_ = swv[t_loc];
      float hp = acc[jn][r] / (sw_ > 0.f ? sw_ : 1.f);
      hp = hp > 0.f ? hp : (__expf(hp) - 1.f);
      float o = hp >= 0.f ? sqrtf(hp) : -sqrtf(-hp);
      ssum += o * o;
      t2b[(b * NT + t0 + t_loc) * ND + (bh & 7) * 64 + 16*jn + lr] = f2bf(o);
    }
    ssum += __shfl_xor(ssum, 16, 64);
    ssum += __shfl_xor(ssum, 32, 64);
    if (quad == 0) atomicAdd(&cn[b * ND + (bh & 7) * 64 + 16*jn + lr], ssum);
  }
}

// ---------- GEMM2: Y = (t2b*scl) @ W2 + x + b2 ; tile 128 x 64 ; fused LN partials
//   A from bf16 t2b (scaled at LDS-store); B staged COALESCED from f32 W2[k][n]
//   with LDS-transposed swizzled write.
__launch_bounds__(256, 3)
__global__ void k_gemm2(const u16* __restrict__ A, const float* __restrict__ W2f,
                        const float* __restrict__ xres, const float* __restrict__ b2,
                        const float* __restrict__ cn, float* __restrict__ Y,
                        float* __restrict__ rsum, float* __restrict__ rqsum){
  __shared__ u16 As[128 * 40];
  __shared__ u16 Bs[64 * 40];
  __shared__ float scl[512];
  int m0 = blockIdx.x * 128, n0 = blockIdx.y * 64;
  int tid = threadIdx.x;
  int wv = tid >> 6, lane = tid & 63;
  int quad = lane >> 4, lr = lane & 15;
  int bb0 = (m0 >> 10) << 9;          // b*512
  for (int i = tid; i < 512; i += 256){
    float nv = sqrtf(cn[bb0 + i]);
    scl[i] = 1.f / fmaxf(nv, 1e-12f);
  }
  f32x4 acc[2][4] = {};
  int ar = (tid * 8) >> 5, ac = (tid * 8) & 31;
  const u16* ap0 = &A[(size_t)(m0 + ar) * 512 + ac];
  const u16* ap1 = ap0 + (size_t)64 * 512;
  int kk = (tid * 8) >> 6, j0 = (tid * 8) & 63;
  const float* w2b = &W2f[(size_t)kk * 512 + n0 + j0];
  int bbase = j0 * 40 + (((kk >> 3) ^ ((j0 >> 3) & 3)) * 8) + (kk & 7);
  bf16x8 ra0 = *(const bf16x8*)ap0;
  bf16x8 ra1 = *(const bf16x8*)ap1;
  f32x4 pb0 = *(const f32x4*)w2b, pb1 = *(const f32x4*)(w2b + 4);
  for (int kt = 0; kt < 512; kt += 32){
    __syncthreads();
    {
      u16 pk0[8], pk1[8];
#pragma unroll
      for (int q = 0; q < 8; q++){
        float sv = scl[kt + ac + q];
        pk0[q] = f2bf(bf2f((u16)ra0[q]) * sv);
        pk1[q] = f2bf(bf2f((u16)ra1[q]) * sv);
      }
      *(bf16x8*)&As[ar*40 + ac]        = *(const bf16x8*)pk0;
      *(bf16x8*)&As[(ar + 64)*40 + ac] = *(const bf16x8*)pk1;
#pragma unroll
      for (int q = 0; q < 4; q++) Bs[bbase + q*40]     = f2bf(pb0[q]);
#pragma unroll
      for (int q = 0; q < 4; q++) Bs[bbase + (q+4)*40] = f2bf(pb1[q]);
    }
    __syncthreads();
    if (kt < 480){
      ra0 = *(const bf16x8*)(ap0 + kt + 32);
      ra1 = *(const bf16x8*)(ap1 + kt + 32);
      pb0 = *(const f32x4*)(w2b + (size_t)(kt + 32) * 512);
      pb1 = *(const f32x4*)(w2b + (size_t)(kt + 32) * 512 + 4);
    }
    bf16x8 af[2], bfr[4];
#pragma unroll
    for (int i = 0; i < 2; i++) af[i] = *(const bf16x8*)&As[(wv*32 + i*16 + lr)*40 + quad*8];
#pragma unroll
    for (int i = 0; i < 4; i++){
      int f = i*16 + lr;
      bfr[i] = *(const bf16x8*)&Bs[f*40 + ((quad ^ ((f >> 3) & 3)) * 8)];
    }
#pragma unroll
    for (int mi = 0; mi < 2; mi++)
#pragma unroll
      for (int ni = 0; ni < 4; ni++)
        acc[mi][ni] = __builtin_amdgcn_mfma_f32_16x16x32_bf16(af[mi], bfr[ni], acc[mi][ni], 0, 0, 0);
  }
  float b2v[4];
#pragma unroll
  for (int ni = 0; ni < 4; ni++) b2v[ni] = b2[n0 + ni*16 + lr];
#pragma unroll
  for (int mi = 0; mi < 2; mi++){
    int rgb = m0 + wv*32 + mi*16 + quad*4;
#pragma unroll
    for (int r = 0; r < 4; r++){
      int row = rgb + r;
      float rs = 0.f, rq = 0.f;
#pragma unroll
      for (int ni = 0; ni < 4; ni++){
        int cg = n0 + ni*16 + lr;
        int idx = row * 512 + cg;
        float yv = acc[mi][ni][r] + xres[idx] + b2v[ni];
        Y[idx] = yv;
        rs += yv; rq += yv * yv;
      }
#pragma unroll
      for (int m2 = 1; m2 < 16; m2 <<= 1){
        rs += __shfl_xor(rs, m2, 64);
        rq += __shfl_xor(rq, m2, 64);
      }
      if (lr == 0){
        atomicAdd(&rsum[row], rs);
        atomicAdd(&rqsum[row], rq);
      }
    }
  }
}

// ---------- LN apply (stats precomputed) + transpose; block = 64 t x 128 d
__global__ void k_outln(const float* __restrict__ Y, const float* __restrict__ rsum,
                        const float* __restrict__ rqsum, const float* __restrict__ g,
                        const float* __restrict__ bb, float* __restrict__ out){
  __shared__ float mus[64], rss[64];
  __shared__ float tile[64 * 65];
  int t0 = blockIdx.x * 64, b = blockIdx.y;
  int cbase = blockIdx.z * 128;
  int tid = threadIdx.x;
  if (tid < 64){
    int row = b * NT + t0 + tid;
    float m = rsum[row] * (1.f/512.f);
    float var = rqsum[row] * (1.f/512.f) - m * m;
    mus[tid] = m;
    rss[tid] = 1.f / sqrtf(var + 1e-5f);
  }
  __syncthreads();
  int j = tid & 63, i0 = tid >> 6;
  for (int c0 = cbase; c0 < cbase + 128; c0 += 64){
#pragma unroll
    for (int k = 0; k < 16; k++){
      int i = i0 + k * 4;
      float v = (Y[(b * NT + t0 + i) * ND + c0 + j] - mus[i]) * rss[i] * g[c0 + j] + bb[c0 + j];
      tile[i * 65 + j] = v;
    }
    __syncthreads();
#pragma unroll
    for (int k = 0; k < 16; k++){
      int jj = i0 + k * 4;   // d-local
      out[(b * ND + c0 + jj) * NT + t0 + j] = tile[j * 65 + jj];
    }
    __syncthreads();
  }
}

extern "C" void kernel_launch(void* const* d_in, const int* in_sizes, int n_in,
                              void* d_out, int out_size, void* d_ws, size_t ws_size,
                              hipStream_t stream) {
  (void)in_sizes; (void)n_in; (void)out_size; (void)ws_size;
  const float* x     = (const float*)d_in[0];
  const float* W     = (const float*)d_in[1];
  const float* a_src = (const float*)d_in[2];
  const float* a_dst = (const float*)d_in[3];
  const float* W2    = (const float*)d_in[4];
  const float* b2    = (const float*)d_in[5];
  const float* ln_g  = (const float*)d_in[6];
  const float* ln_b  = (const float*)d_in[7];
  char* ws = (char*)d_ws;
  int*   sel   = (int*)  (ws + 256);
  float* mags  = (float*)(ws + 33024);
  float* es    = (float*)(ws + 1124608);
  float* ed    = (float*)(ws + 1386752);
  float* cn    = (float*)(ws + 1648896);   // 16 KB (zeroed in k_gemm_wh h==0 blocks)
  float* rsum  = (float*)(ws + 1665280);   // 32 KB (zeroed in k_gemm_wh h==1 blocks)
  float* rqsum = (float*)(ws + 1698048);   // 32 KB (contiguous with rsum)
  u16*   WhT   = (u16*)  (ws + 2097152);   // 8 MB; dead after k_attn
  u16*   t2b   = (u16*)  (ws + 18874368);  // 8 MB
  float* Y     = (float*)(ws + 2097152);   // 16 MB; overlays WhT after dead
  float* out   = (float*)d_out;

  k_gemm_wh  <<<dim3(64, 8), 256, 0, stream>>>(x, W, a_src, a_dst, WhT, es, ed, mags, cn, rsum);
  k_select   <<<dim3(NB, 16), 256, 0, stream>>>(mags, sel);
  k_attn     <<<dim3(64, 16), 256, 0, stream>>>(WhT, es, ed, sel, t2b, cn);
  k_gemm2    <<<dim3(64, 8), 256, 0, stream>>>(t2b, W2, x, b2, cn, Y, rsum, rqsum);
  k_outln    <<<dim3(16, NB, 4), 256, 0, stream>>>(Y, rsum, rqsum, ln_g, ln_b, out);
}